// Round 5
// baseline (61.243 us; speedup 1.0000x reference)
//
#include <hip/hip_runtime.h>

#define NN 16
#define NO 32
#define XCOLS 133

typedef _Float16 h2 __attribute__((ext_vector_type(2)));

static __device__ __forceinline__ h2 pk(float a, float b) {
    return __builtin_bit_cast(h2, __builtin_amdgcn_cvt_pkrtz(a, b));
}
static __device__ __forceinline__ float dot2(h2 a, h2 b, float c) {
    return __builtin_amdgcn_fdot2(a, b, c, false);
}
static __device__ __forceinline__ unsigned h2u(h2 v) { return __builtin_bit_cast(unsigned, v); }
static __device__ __forceinline__ h2 u2h(unsigned v) { return __builtin_bit_cast(h2, v); }

// packed-weight layout in d_ws (dword offsets); pairs along the contraction dim
#define OFF_PNW1 0     // [2][64]
#define OFF_PNW2 128   // [32][16]
#define OFF_RNW1 640   // [8][64]
#define OFF_RNW2 1152  // [32][8]
#define OFF_POW1 1408  // [1][64]
#define OFF_POW2 1472  // [32][16]
#define OFF_ROW1 1984  // [8][64]
#define OFF_ROW2 2496  // [32][8]
#define OFF_PSW1 2752  // [9][64]
#define OFF_PSW2 3328  // [32][64]
#define OFF_PSW3 5376  // [32][2]

__global__ void prep_weights(
    const float* __restrict__ pnW1, const float* __restrict__ pnW2,
    const float* __restrict__ rnW1, const float* __restrict__ rnW2,
    const float* __restrict__ poW1, const float* __restrict__ poW2,
    const float* __restrict__ roW1, const float* __restrict__ roW2,
    const float* __restrict__ psW1, const float* __restrict__ psW2,
    const float* __restrict__ psW3, unsigned* __restrict__ ws)
{
    const float* ins[11]  = {pnW1, pnW2, rnW1, rnW2, poW1, poW2, roW1, roW2, psW1, psW2, psW3};
    const int offs[11]    = {OFF_PNW1, OFF_PNW2, OFF_RNW1, OFF_RNW2, OFF_POW1, OFF_POW2,
                             OFF_ROW1, OFF_ROW2, OFF_PSW1, OFF_PSW2, OFF_PSW3};
    const int pairsv[11]  = {2, 32, 8, 32, 1, 32, 8, 32, 9, 32, 32};
    const int colsv[11]   = {64, 16, 64, 8, 64, 16, 64, 8, 64, 64, 2};
    for (int a = 0; a < 11; ++a) {
        const float* in = ins[a];
        const int C = colsv[a], n = pairsv[a] * C, off = offs[a];
        for (int i = threadIdx.x; i < n; i += blockDim.x) {
            const int p = i / C, c = i - p * C;
            ws[off + i] = h2u(pk(in[(2 * p) * C + c], in[(2 * p + 1) * C + c]));
        }
    }
}

// xs swizzle: pair-column cp in [0,32), element e in [0,64)
#define XS(cp, e) ((cp) * 64 + ((e) ^ (cp)))

// 512 threads = 8 waves; wave w owns features [8w, 8w+8) of every 64-wide layer.
// Cross-wave partials as packed-f16 pairs in bufU (slot-recycled, barrier-separated):
//   pn: slots 4-11 (w P1, r P2) | rn: 0-3 (w P2, r P3) | po: 4-11 (w P3, r P4)
//   ro: 0-3 (w P4, r P5)        | ha: 4-7 (w P5, r P6)
__global__ __launch_bounds__(512, 8) void barrier_net_kernel(
    const float* __restrict__ x, const float* __restrict__ noise,
    const float* __restrict__ pnb1, const float* __restrict__ pnb2,
    const float* __restrict__ rnb1, const float* __restrict__ rnb2,
    const float* __restrict__ pob1, const float* __restrict__ pob2,
    const float* __restrict__ rob1, const float* __restrict__ rob2,
    const float* __restrict__ psb1, const float* __restrict__ psb2,
    const float* __restrict__ psb3,
    const unsigned* __restrict__ wsu,
    float* __restrict__ out)
{
    __shared__ unsigned xsN[2048];        // 8 KB neighbor pairs
    __shared__ unsigned xsO[2048];        // 8 KB obstacle pairs
    __shared__ unsigned bufU[12][8][64];  // 12 KB packed partials [slot][wave][elem]
    __shared__ float4  bufF[8][64];       // 8 KB finale partials        -> 36 KB

    const int tid = threadIdx.x;
    const int l   = tid & 63;
    const int w   = __builtin_amdgcn_readfirstlane(tid >> 6);
    const int fb  = w * 8;    // feature base of this wave's slice
    const int fp0 = w * 4;    // first feature-pair index of slice
    const int e0  = blockIdx.x * 64;

    const float g0 = x[(size_t)(e0 + l) * XCOLS + 1];
    const float g1 = x[(size_t)(e0 + l) * XCOLS + 2];
    const float* __restrict__ src = x + (size_t)e0 * XCOLS;

    // ---- stage BOTH point blocks as f16 pairs
    #pragma unroll
    for (int it = 0; it < 4; ++it) {
        const int idx = it * 512 + tid;   // 0..2047
        const int ee  = idx >> 5;
        const int cp  = idx & 31;
        const float* pN = src + (size_t)ee * XCOLS + 5 + 2 * cp;
        xsN[XS(cp, ee)] = h2u(pk(pN[0], pN[1]));
        const float* pO = src + (size_t)ee * XCOLS + 69 + 2 * cp;
        xsO[XS(cp, ee)] = h2u(pk(pO[0], pO[1]));
    }
    __syncthreads();  // B1

    float bar0 = 0.f, bar1 = 0.f;

    // ============ P1: neighbor L1 slice + pn partial + barrier(2j) ============
    {
        float sn[8];
        #pragma unroll
        for (int f = 0; f < 8; ++f) sn[f] = 0.f;
        #pragma unroll 4
        for (int j = 0; j < NN; ++j) {
            const h2 h01 = u2h(xsN[XS(2 * j, l)]);
            const h2 h23 = u2h(xsN[XS(2 * j + 1, l)]);
            #pragma unroll
            for (int f = 0; f < 8; ++f) {
                float t = dot2(h01, u2h(wsu[OFF_PNW1 + fb + f]), pnb1[fb + f]);
                t = dot2(h23, u2h(wsu[OFF_PNW1 + 64 + fb + f]), t);
                sn[f] += fmaxf(t, 0.f);
            }
        }
        #pragma unroll
        for (int jj = 0; jj < 2; ++jj) {
            const h2 h01 = u2h(xsN[XS(2 * (2 * w + jj), l)]);
            const float v0 = (float)h01[0], v1 = (float)h01[1];
            const float nrm = sqrtf(v0 * v0 + v1 * v1);
            const float cc  = 0.01f * __builtin_amdgcn_rcpf(nrm * (nrm - 0.3f));
            bar0 -= cc * v0;
            bar1 -= cc * v1;
        }
        h2 snp[4];
        #pragma unroll
        for (int i = 0; i < 4; ++i) snp[i] = pk(sn[2 * i], sn[2 * i + 1]);
        float pn[16];
        #pragma unroll
        for (int q = 0; q < 16; ++q) pn[q] = 0.f;
        #pragma unroll
        for (int i = 0; i < 4; ++i) {
            #pragma unroll
            for (int q = 0; q < 16; ++q)
                pn[q] = dot2(snp[i], u2h(wsu[OFF_PNW2 + (fp0 + i) * 16 + q]), pn[q]);
        }
        #pragma unroll
        for (int p = 0; p < 8; ++p)
            bufU[4 + p][w][l] = h2u(pk(pn[2 * p], pn[2 * p + 1]));
    }
    __syncthreads();  // B2

    // ============ P2: pn full (pairs) -> rn partial ============
    {
        h2 pnp[8];
        #pragma unroll
        for (int p = 0; p < 8; ++p) {
            h2 acc = pk(16.f * pnb2[2 * p], 16.f * pnb2[2 * p + 1]);
            #pragma unroll
            for (int w2 = 0; w2 < 8; ++w2) acc = acc + u2h(bufU[4 + p][w2][l]);
            pnp[p] = acc;
        }
        float tv[8];
        #pragma unroll
        for (int f = 0; f < 8; ++f) {
            float t = rnb1[fb + f];
            #pragma unroll
            for (int p = 0; p < 8; ++p)
                t = dot2(pnp[p], u2h(wsu[OFF_RNW1 + p * 64 + fb + f]), t);
            tv[f] = fmaxf(t, 0.f);
        }
        h2 tp[4];
        #pragma unroll
        for (int i = 0; i < 4; ++i) tp[i] = pk(tv[2 * i], tv[2 * i + 1]);
        float rp[8];
        #pragma unroll
        for (int r = 0; r < 8; ++r) rp[r] = 0.f;
        #pragma unroll
        for (int i = 0; i < 4; ++i) {
            #pragma unroll
            for (int r = 0; r < 8; ++r)
                rp[r] = dot2(tp[i], u2h(wsu[OFF_RNW2 + (fp0 + i) * 8 + r]), rp[r]);
        }
        #pragma unroll
        for (int p = 0; p < 4; ++p)
            bufU[p][w][l] = h2u(pk(rp[2 * p], rp[2 * p + 1]));
    }
    __syncthreads();  // B3

    // ============ P3: rn full; obstacle L1 slice + po partial + barrier(4j) ===
    h2 rnp[4];
    {
        #pragma unroll
        for (int p = 0; p < 4; ++p) {
            h2 acc = pk(rnb2[2 * p], rnb2[2 * p + 1]);
            #pragma unroll
            for (int w2 = 0; w2 < 8; ++w2) acc = acc + u2h(bufU[p][w2][l]);
            rnp[p] = acc;
        }
        float so[8];
        #pragma unroll
        for (int f = 0; f < 8; ++f) so[f] = 0.f;
        #pragma unroll 4
        for (int j = 0; j < NO; ++j) {
            const h2 hp2 = u2h(xsO[XS(j, l)]);
            #pragma unroll
            for (int f = 0; f < 8; ++f) {
                const float t = dot2(hp2, u2h(wsu[OFF_POW1 + fb + f]), pob1[fb + f]);
                so[f] += fmaxf(t, 0.f);
            }
        }
        #pragma unroll
        for (int jj = 0; jj < 4; ++jj) {
            const h2 hp2 = u2h(xsO[XS(4 * w + jj, l)]);
            const float v0 = (float)hp2[0], v1 = (float)hp2[1];
            const float nrm = sqrtf(v0 * v0 + v1 * v1);
            const float cc  = 0.01f * __builtin_amdgcn_rcpf(nrm * (nrm - 0.5f));
            bar0 -= cc * v0;
            bar1 -= cc * v1;
        }
        h2 sop[4];
        #pragma unroll
        for (int i = 0; i < 4; ++i) sop[i] = pk(so[2 * i], so[2 * i + 1]);
        float po[16];
        #pragma unroll
        for (int q = 0; q < 16; ++q) po[q] = 0.f;
        #pragma unroll
        for (int i = 0; i < 4; ++i) {
            #pragma unroll
            for (int q = 0; q < 16; ++q)
                po[q] = dot2(sop[i], u2h(wsu[OFF_POW2 + (fp0 + i) * 16 + q]), po[q]);
        }
        #pragma unroll
        for (int p = 0; p < 8; ++p)
            bufU[4 + p][w][l] = h2u(pk(po[2 * p], po[2 * p + 1]));
    }
    __syncthreads();  // B4

    // ============ P4: po full (pairs) -> ro partial ============
    {
        h2 pop[8];
        #pragma unroll
        for (int p = 0; p < 8; ++p) {
            h2 acc = pk(32.f * pob2[2 * p], 32.f * pob2[2 * p + 1]);
            #pragma unroll
            for (int w2 = 0; w2 < 8; ++w2) acc = acc + u2h(bufU[4 + p][w2][l]);
            pop[p] = acc;
        }
        float tv[8];
        #pragma unroll
        for (int f = 0; f < 8; ++f) {
            float t = rob1[fb + f];
            #pragma unroll
            for (int p = 0; p < 8; ++p)
                t = dot2(pop[p], u2h(wsu[OFF_ROW1 + p * 64 + fb + f]), t);
            tv[f] = fmaxf(t, 0.f);
        }
        h2 tp[4];
        #pragma unroll
        for (int i = 0; i < 4; ++i) tp[i] = pk(tv[2 * i], tv[2 * i + 1]);
        float op[8];
        #pragma unroll
        for (int r = 0; r < 8; ++r) op[r] = 0.f;
        #pragma unroll
        for (int i = 0; i < 4; ++i) {
            #pragma unroll
            for (int r = 0; r < 8; ++r)
                op[r] = dot2(tp[i], u2h(wsu[OFF_ROW2 + (fp0 + i) * 8 + r]), op[r]);
        }
        #pragma unroll
        for (int p = 0; p < 4; ++p)
            bufU[p][w][l] = h2u(pk(op[2 * p], op[2 * p + 1]));
    }
    __syncthreads();  // B5

    // ============ P5: ro full; psi L1 slice ============
    {
        h2 hp[9];
        #pragma unroll
        for (int p = 0; p < 4; ++p) hp[p] = rnp[p];
        #pragma unroll
        for (int p = 0; p < 4; ++p) {
            h2 acc = pk(rob2[2 * p], rob2[2 * p + 1]);
            #pragma unroll
            for (int w2 = 0; w2 < 8; ++w2) acc = acc + u2h(bufU[p][w2][l]);
            hp[4 + p] = acc;
        }
        hp[8] = pk(g0, g1);
        float ha[8];
        #pragma unroll
        for (int f = 0; f < 8; ++f) {
            float t = psb1[fb + f];
            #pragma unroll
            for (int p = 0; p < 9; ++p)
                t = dot2(hp[p], u2h(wsu[OFF_PSW1 + p * 64 + fb + f]), t);
            ha[f] = fmaxf(t, 0.f);
        }
        #pragma unroll
        for (int p = 0; p < 4; ++p)
            bufU[4 + p][w][l] = h2u(pk(ha[2 * p], ha[2 * p + 1]));
    }
    __syncthreads();  // B6

    // ============ P6: psi L2 slice + L3 partials ============
    {
        float t2[8];
        #pragma unroll
        for (int f2 = 0; f2 < 8; ++f2) t2[f2] = psb2[fb + f2];
        #pragma unroll 8
        for (int pg = 0; pg < 32; ++pg) {
            const h2 hap = u2h(bufU[4 + (pg & 3)][pg >> 2][l]);
            #pragma unroll
            for (int f2 = 0; f2 < 8; ++f2)
                t2[f2] = dot2(hap, u2h(wsu[OFF_PSW2 + pg * 64 + fb + f2]), t2[f2]);
        }
        h2 tpp[4];
        #pragma unroll
        for (int i = 0; i < 4; ++i)
            tpp[i] = pk(fmaxf(t2[2 * i], 0.f), fmaxf(t2[2 * i + 1], 0.f));
        float o0p = 0.f, o1p = 0.f;
        #pragma unroll
        for (int i = 0; i < 4; ++i) {
            o0p = dot2(tpp[i], u2h(wsu[OFF_PSW3 + (fp0 + i) * 2 + 0]), o0p);
            o1p = dot2(tpp[i], u2h(wsu[OFF_PSW3 + (fp0 + i) * 2 + 1]), o1p);
        }
        bufF[w][l] = make_float4(o0p, o1p, bar0, bar1);
    }
    __syncthreads();  // B7

    // ============ P7: finale (128 threads, one tanh chain each) ============
    if (tid < 128) {
        const int elem = tid >> 1;
        const int oi   = tid & 1;
        float o = psb3[oi], bb = 0.f;
        #pragma unroll
        for (int w2 = 0; w2 < 8; ++w2) {
            const float4 v = bufF[w2][elem];
            o  += oi ? v.y : v.x;
            bb += oi ? v.w : v.z;
        }
        const float e_ = 2.f * tanhf(o);
        const float av = tanhf(e_ + bb + noise[2 * (size_t)e0 + tid]);
        out[2 * (size_t)e0 + tid] = 2.f * av;
    }
}

extern "C" void kernel_launch(void* const* d_in, const int* in_sizes, int n_in,
                              void* d_out, int out_size, void* d_ws, size_t ws_size,
                              hipStream_t stream) {
    const float* x    = (const float*)d_in[0];
    const float* nz   = (const float*)d_in[1];
    const float* pnW1 = (const float*)d_in[2];
    const float* pnb1 = (const float*)d_in[3];
    const float* pnW2 = (const float*)d_in[4];
    const float* pnb2 = (const float*)d_in[5];
    const float* rnW1 = (const float*)d_in[6];
    const float* rnb1 = (const float*)d_in[7];
    const float* rnW2 = (const float*)d_in[8];
    const float* rnb2 = (const float*)d_in[9];
    const float* poW1 = (const float*)d_in[10];
    const float* pob1 = (const float*)d_in[11];
    const float* poW2 = (const float*)d_in[12];
    const float* pob2 = (const float*)d_in[13];
    const float* roW1 = (const float*)d_in[14];
    const float* rob1 = (const float*)d_in[15];
    const float* roW2 = (const float*)d_in[16];
    const float* rob2 = (const float*)d_in[17];
    const float* psW1 = (const float*)d_in[18];
    const float* psb1 = (const float*)d_in[19];
    const float* psW2 = (const float*)d_in[20];
    const float* psb2 = (const float*)d_in[21];
    const float* psW3 = (const float*)d_in[22];
    const float* psb3 = (const float*)d_in[23];

    unsigned* ws = (unsigned*)d_ws;
    hipLaunchKernelGGL(prep_weights, dim3(1), dim3(256), 0, stream,
        pnW1, pnW2, rnW1, rnW2, poW1, poW2, roW1, roW2, psW1, psW2, psW3, ws);

    const int b = in_sizes[0] / XCOLS;
    hipLaunchKernelGGL(barrier_net_kernel, dim3(b / 64), dim3(512), 0, stream,
        x, nz, pnb1, pnb2, rnb1, rnb2, pob1, pob2, rob1, rob2,
        psb1, psb2, psb3, ws, (float*)d_out);
}